// Round 3
// baseline (1471.374 us; speedup 1.0000x reference)
//
#include <hip/hip_runtime.h>
#include <hip/hip_bf16.h>

// Problem constants
#define BQ 64          // query rows per block
#define NS 16          // N-chunks
#define CH 6250        // N / NS (exact: 16*6250 = 100000)
#define BD 128         // D
#define NC 100         // classes
#define CP 112         // padded classes (7 * 16)
#define KV 32          // address rows per tile
#define AST 136        // A-tile LDS row stride (bf16 elems): 272B, 16B-aligned, conflict-light
#define MST 40         // Mt LDS row stride: 80B, 16B-aligned
#define PST 40         // P LDS row stride
#define LOG2E 1.4426950408889634f

typedef short short8 __attribute__((ext_vector_type(8)));
typedef float f32x4 __attribute__((ext_vector_type(4)));

__device__ __forceinline__ unsigned short f2bf(float f) {
    union { float f; unsigned u; } v; v.f = f;
    unsigned r = v.u + 0x7FFFu + ((v.u >> 16) & 1u);
    return (unsigned short)(r >> 16);
}

__global__ __launch_bounds__(256, 2) void fused_main(
    const float* __restrict__ x, const float* __restrict__ A,
    const float* __restrict__ M, float* __restrict__ pO,
    float* __restrict__ pM, float* __restrict__ pL)
{
    __shared__ __align__(16) unsigned short a_lds[KV * AST];
    __shared__ __align__(16) unsigned short mt_lds[CP * MST];
    __shared__ __align__(16) unsigned short p_lds[4][16 * PST];
    __shared__ float anorm[KV];

    const int tid  = threadIdx.x;
    const int wave = tid >> 6, lane = tid & 63;
    const int l15  = lane & 15, lhi = lane >> 4;
    const int bid  = blockIdx.x;
    const int chunk = bid & (NS - 1);
    const int rg    = bid >> 4;
    const int n0c   = chunk * CH;
    const int n1c   = n0c + CH;
    const int qbase = rg * BQ + wave * 16;
    const int q     = qbase + l15;

    // ---- Q fragments (bf16) + row norms ||x_q||^2
    short8 qf[4];
    float sumsq = 0.f;
    #pragma unroll
    for (int kk = 0; kk < 4; ++kk) {
        const float* xp = x + (size_t)q * BD + kk * 32 + lhi * 8;
        float4 v0 = *(const float4*)xp;
        float4 v1 = *(const float4*)(xp + 4);
        short8 f;
        f[0] = (short)f2bf(v0.x); f[1] = (short)f2bf(v0.y);
        f[2] = (short)f2bf(v0.z); f[3] = (short)f2bf(v0.w);
        f[4] = (short)f2bf(v1.x); f[5] = (short)f2bf(v1.y);
        f[6] = (short)f2bf(v1.z); f[7] = (short)f2bf(v1.w);
        qf[kk] = f;
        sumsq += v0.x*v0.x + v0.y*v0.y + v0.z*v0.z + v0.w*v0.w
               + v1.x*v1.x + v1.y*v1.y + v1.z*v1.z + v1.w*v1.w;
    }
    sumsq += __shfl_xor(sumsq, 16);
    sumsq += __shfl_xor(sumsq, 32);
    float nxr[4];
    #pragma unroll
    for (int r2 = 0; r2 < 4; ++r2) nxr[r2] = __shfl(sumsq, lhi * 4 + r2);

    const f32x4 zf = {0.f, 0.f, 0.f, 0.f};
    f32x4 Oacc[7];
    #pragma unroll
    for (int c = 0; c < 7; ++c) Oacc[c] = zf;
    float mrow[4] = {-1e30f, -1e30f, -1e30f, -1e30f};
    float lrow[4] = {0.f, 0.f, 0.f, 0.f};

    for (int n0 = n0c; n0 < n1c; n0 += KV) {
        __syncthreads();   // previous iter's LDS reads done before restage
        // ---- stage A tile (f32 -> bf16) + row norms
        {
            int arow = tid >> 3, seg = tid & 7;
            int n = n0 + arow;
            float s2 = 0.f;
            unsigned short* dst = &a_lds[arow * AST + seg * 16];
            if (n < n1c) {
                const float* src = A + (size_t)n * BD + seg * 16;
                #pragma unroll
                for (int j = 0; j < 4; ++j) {
                    float4 v = ((const float4*)src)[j];
                    dst[j*4+0] = f2bf(v.x); dst[j*4+1] = f2bf(v.y);
                    dst[j*4+2] = f2bf(v.z); dst[j*4+3] = f2bf(v.w);
                    s2 += v.x*v.x + v.y*v.y + v.z*v.z + v.w*v.w;
                }
            } else {
                #pragma unroll
                for (int j = 0; j < 16; ++j) dst[j] = 0;
            }
            s2 += __shfl_xor(s2, 1);
            s2 += __shfl_xor(s2, 2);
            s2 += __shfl_xor(s2, 4);
            if (seg == 0) anorm[arow] = (n < n1c) ? s2 : 1e18f;
        }
        // ---- stage M tile transposed: Mt[c][n], zero-padded
        #pragma unroll
        for (int it = 0; it < 14; ++it) {
            int idx = tid + it * 256;
            int r2 = idx / CP;
            int c  = idx - r2 * CP;
            int n  = n0 + r2;
            float v = (c < NC && n < n1c) ? M[(size_t)n * NC + c] : 0.f;
            mt_lds[c * MST + r2] = f2bf(v);
        }
        __syncthreads();

        // ---- QK^T : S[q][n] (two 16x16 n-subtiles)
        f32x4 s[2]; s[0] = zf; s[1] = zf;
        #pragma unroll
        for (int t = 0; t < 2; ++t) {
            #pragma unroll
            for (int kk = 0; kk < 4; ++kk) {
                short8 bf = *(const short8*)&a_lds[(t*16 + l15) * AST + kk*32 + lhi*8];
                s[t] = __builtin_amdgcn_mfma_f32_16x16x32_bf16(qf[kk], bf, s[t], 0, 0, 0);
            }
        }
        float na0 = anorm[l15], na1 = anorm[16 + l15];

        // ---- online softmax (rows spread across regs; cols across 16-lane groups)
        float pv0[4], pv1[4], fr[4];
        #pragma unroll
        for (int r2 = 0; r2 < 4; ++r2) {
            float s0 = nxr[r2] + na0 - 2.f * s[0][r2];
            float s1 = nxr[r2] + na1 - 2.f * s[1][r2];
            s0 = -0.5f * sqrtf(fmaxf(s0, 0.f));   // -dist/T, T=2
            s1 = -0.5f * sqrtf(fmaxf(s1, 0.f));
            float v = fmaxf(s0, s1);
            v = fmaxf(v, __shfl_xor(v, 1));
            v = fmaxf(v, __shfl_xor(v, 2));
            v = fmaxf(v, __shfl_xor(v, 4));
            v = fmaxf(v, __shfl_xor(v, 8));
            float mnew = fmaxf(mrow[r2], v);
            float f = exp2f((mrow[r2] - mnew) * LOG2E);
            mrow[r2] = mnew;
            float p0 = exp2f((s0 - mnew) * LOG2E);
            float p1 = exp2f((s1 - mnew) * LOG2E);
            pv0[r2] = p0; pv1[r2] = p1;
            float ps = p0 + p1;
            ps += __shfl_xor(ps, 1);
            ps += __shfl_xor(ps, 2);
            ps += __shfl_xor(ps, 4);
            ps += __shfl_xor(ps, 8);
            lrow[r2] = lrow[r2] * f + ps;
            fr[r2] = f;
        }
        #pragma unroll
        for (int c = 0; c < 7; ++c)
            #pragma unroll
            for (int r2 = 0; r2 < 4; ++r2) Oacc[c][r2] *= fr[r2];

        // ---- P -> LDS (C/D layout) then reload as A-frag layout
        #pragma unroll
        for (int r2 = 0; r2 < 4; ++r2) {
            p_lds[wave][(lhi*4 + r2) * PST +  0 + l15] = f2bf(pv0[r2]);
            p_lds[wave][(lhi*4 + r2) * PST + 16 + l15] = f2bf(pv1[r2]);
        }
        short8 pa = *(const short8*)&p_lds[wave][l15 * PST + lhi * 8];
        // ---- PV: Oacc[q][c] += P[q][n] * M[n][c]
        #pragma unroll
        for (int c = 0; c < 7; ++c) {
            short8 bm = *(const short8*)&mt_lds[(c*16 + l15) * MST + lhi * 8];
            Oacc[c] = __builtin_amdgcn_mfma_f32_16x16x32_bf16(pa, bm, Oacc[c], 0, 0, 0);
        }
    }

    // ---- write partials (unnormalized O, m, l)
    const size_t crow = (size_t)chunk * 2048;
    #pragma unroll
    for (int c = 0; c < 7; ++c) {
        #pragma unroll
        for (int r2 = 0; r2 < 4; ++r2) {
            int row = qbase + lhi * 4 + r2;
            pO[(crow + row) * CP + c * 16 + l15] = Oacc[c][r2];
        }
    }
    if (l15 == 0) {
        #pragma unroll
        for (int r2 = 0; r2 < 4; ++r2) {
            int row = qbase + lhi * 4 + r2;
            pM[crow + row] = mrow[r2];
            pL[crow + row] = lrow[r2];
        }
    }
}

__global__ __launch_bounds__(128) void combine(
    const float* __restrict__ pO, const float* __restrict__ pM,
    const float* __restrict__ pL, float* __restrict__ out)
{
    int r = blockIdx.x;
    int c = threadIdx.x;
    float mi[NS];
    float mg = -1e30f;
    #pragma unroll
    for (int i = 0; i < NS; ++i) { mi[i] = pM[i * 2048 + r]; mg = fmaxf(mg, mi[i]); }
    float w[NS];
    float lg = 0.f;
    #pragma unroll
    for (int i = 0; i < NS; ++i) {
        w[i] = exp2f((mi[i] - mg) * LOG2E);
        lg += pL[i * 2048 + r] * w[i];
    }
    if (c < NC) {
        float acc = 0.f;
        #pragma unroll
        for (int i = 0; i < NS; ++i)
            acc += pO[((size_t)i * 2048 + r) * CP + c] * w[i];
        out[(size_t)r * NC + c] = acc / lg;
    }
}

extern "C" void kernel_launch(void* const* d_in, const int* in_sizes, int n_in,
                              void* d_out, int out_size, void* d_ws, size_t ws_size,
                              hipStream_t stream) {
    const float* x = (const float*)d_in[0];
    const float* A = (const float*)d_in[1];
    const float* M = (const float*)d_in[2];
    float* out = (float*)d_out;
    float* pO = (float*)d_ws;                                  // NS*2048*112 f32
    float* pM = pO + (size_t)NS * 2048 * CP;                   // NS*2048 f32
    float* pL = pM + (size_t)NS * 2048;                        // NS*2048 f32
    fused_main<<<512, 256, 0, stream>>>(x, A, M, pO, pM, pL);
    combine<<<2048, 128, 0, stream>>>(pO, pM, pL, out);
}

// Round 8
// 484.662 us; speedup vs baseline: 3.0359x; 3.0359x over previous
//
#include <hip/hip_runtime.h>

// ---------------- fast-path constants ----------------
#define NTOT 100000
#define BD 128
#define NC 100
#define CP 112
#define NS 32
#define BROWS 2048
#define LOG2E 1.4426950408889634f

typedef short short8 __attribute__((ext_vector_type(8)));
typedef float f32x4 __attribute__((ext_vector_type(4)));

__device__ __forceinline__ unsigned short f2bf(float f) {
    union { float f; unsigned u; } v; v.f = f;
    unsigned r = v.u + 0x7FFFu + ((v.u >> 16) & 1u);
    return (unsigned short)(r >> 16);
}

__device__ __forceinline__ unsigned pkbf(float a, float b) {
    unsigned r;
    asm("v_cvt_pk_bf16_f32 %0, %1, %2" : "=v"(r) : "v"(a), "v"(b));
    return r;
}

__device__ __forceinline__ void gload16(const void* g, void* l) {
    __builtin_amdgcn_global_load_lds((const __attribute__((address_space(1))) void*)g,
                                     (__attribute__((address_space(3))) void*)l, 16, 0, 0);
}

// ---- prep: A (f32) -> Abf (bf16, per-row XOR-swizzled) + anorm = ||A_n||^2
__global__ __launch_bounds__(256) void prep_A(const float* __restrict__ A,
                                              unsigned short* __restrict__ Abf,
                                              float* __restrict__ anorm) {
    const int tid = threadIdx.x;
    const int row = blockIdx.x * 16 + (tid >> 4);
    const int g = tid & 15;
    const float* src = A + (size_t)row * BD + g * 8;
    float4 v0 = *(const float4*)src, v1 = *(const float4*)(src + 4);
    uint4 u;
    u.x = pkbf(v0.x, v0.y); u.y = pkbf(v0.z, v0.w);
    u.z = pkbf(v1.x, v1.y); u.w = pkbf(v1.z, v1.w);
    float ss = v0.x*v0.x + v0.y*v0.y + v0.z*v0.z + v0.w*v0.w
             + v1.x*v1.x + v1.y*v1.y + v1.z*v1.z + v1.w*v1.w;
    ss += __shfl_xor(ss, 1); ss += __shfl_xor(ss, 2);
    ss += __shfl_xor(ss, 4); ss += __shfl_xor(ss, 8);
    *(uint4*)((char*)Abf + (size_t)row * 256 + ((g * 16) ^ ((row & 15) << 4))) = u;
    if (g == 0) anorm[row] = ss;
}

// ---- prep: M (f32 [N][100]) -> Mt (bf16 [112][N], rows 100..111 zero)
__global__ __launch_bounds__(256) void prep_M(const float* __restrict__ M,
                                              unsigned short* __restrict__ Mt) {
    const int n = blockIdx.x * 256 + threadIdx.x;
    if (n >= NTOT) return;
    const int c0 = blockIdx.y * 8;
    #pragma unroll
    for (int j = 0; j < 8; ++j) {
        int c = c0 + j;
        float v = (c < NC) ? M[(size_t)n * NC + c] : 0.f;
        Mt[(size_t)c * NTOT + n] = f2bf(v);
    }
}

__global__ __launch_bounds__(256, 4) void fused_main(
    const float* __restrict__ x, const unsigned short* __restrict__ Abf,
    const float* __restrict__ anorm, const unsigned short* __restrict__ Mt,
    float* __restrict__ pO, float* __restrict__ pL)
{
    __shared__ __align__(16) unsigned short a_lds[2][4096];
    __shared__ __align__(16) unsigned short m_lds[2][3584];
    __shared__ __align__(16) unsigned short p_lds[4][640];

    const int tid = threadIdx.x, wave = tid >> 6, lane = tid & 63;
    const int l15 = lane & 15, lhi = lane >> 4;
    const int bid = blockIdx.x;
    const int chunk = bid & (NS - 1), rg = bid >> 5;
    const int ts = chunk * 97 + (chunk < 21 ? chunk : 21);
    const int tiles = (chunk < 21) ? 98 : 97;
    const int n0c = ts * 32;
    const int qbase = rg * 64 + wave * 16;

    short8 qf[4];
    float nx = 0.f;
    #pragma unroll
    for (int kk = 0; kk < 4; ++kk) {
        const float* xp = x + (size_t)(qbase + l15) * BD + kk * 32 + lhi * 8;
        float4 v0 = *(const float4*)xp, v1 = *(const float4*)(xp + 4);
        uint4 uu;
        uu.x = pkbf(v0.x, v0.y); uu.y = pkbf(v0.z, v0.w);
        uu.z = pkbf(v1.x, v1.y); uu.w = pkbf(v1.z, v1.w);
        qf[kk] = *(short8*)&uu;
        nx += v0.x*v0.x + v0.y*v0.y + v0.z*v0.z + v0.w*v0.w
            + v1.x*v1.x + v1.y*v1.y + v1.z*v1.z + v1.w*v1.w;
    }
    nx += __shfl_xor(nx, 16); nx += __shfl_xor(nx, 32);

    const char* aFix = (const char*)Abf + tid * 16;
    const int r0 = tid >> 2, sg0 = ((tid & 3) - r0 - (r0 >> 2)) & 3;
    const char* mFix0 = (const char*)Mt + (size_t)r0 * (NTOT * 2) + sg0 * 16;
    const int L1 = tid + 256, r1 = L1 >> 2, sg1 = ((L1 & 3) - r1 - (r1 >> 2)) & 3;
    const char* mFix1 = (const char*)Mt + (size_t)r1 * (NTOT * 2) + sg1 * 16;

    auto stage = [&](int buf, int t) {
        const int n0 = n0c + t * 32;
        const char* ab = aFix + (size_t)n0 * 256;
        char* al = (char*)&a_lds[buf][0] + tid * 16;
        gload16(ab, al);
        gload16(ab + 4096, al + 4096);
        gload16(mFix0 + (size_t)n0 * 2, (char*)&m_lds[buf][0] + tid * 16);
        if (tid < 192)
            gload16(mFix1 + (size_t)n0 * 2, (char*)&m_lds[buf][0] + (tid + 256) * 16);
    };

    f32x4 Oacc[7];
    const f32x4 zf = {0.f, 0.f, 0.f, 0.f};
    #pragma unroll
    for (int c0 = 0; c0 < 7; ++c0) Oacc[c0] = zf;
    float lsum = 0.f;

    stage(0, 0);
    __syncthreads();

    for (int it = 0; it < tiles; ++it) {
        const int buf = it & 1;
        const int n0 = n0c + it * 32;
        if (it + 1 < tiles) stage(buf ^ 1, it + 1);

        float an[8];
        #pragma unroll
        for (int j = 0; j < 8; ++j)
            an[j] = anorm[n0 + (j >> 2) * 16 + lhi * 4 + (j & 3)];

        f32x4 s0 = zf, s1 = zf;
        const char* ab = (const char*)&a_lds[buf][0];
        #pragma unroll
        for (int kk = 0; kk < 4; ++kk) {
            const int sw = (kk * 64 + lhi * 16) ^ (l15 << 4);
            short8 b0 = *(const short8*)(ab + l15 * 256 + sw);
            short8 b1 = *(const short8*)(ab + (16 + l15) * 256 + sw);
            s0 = __builtin_amdgcn_mfma_f32_16x16x32_bf16(b0, qf[kk], s0, 0, 0, 0);
            s1 = __builtin_amdgcn_mfma_f32_16x16x32_bf16(b1, qf[kk], s1, 0, 0, 0);
        }

        float p[8];
        #pragma unroll
        for (int j = 0; j < 8; ++j) {
            float sv = (j < 4) ? s0[j & 3] : s1[j & 3];
            float sq = fmaf(sv, -2.f, an[j]) + nx;
            float arg = sqrtf(fmaxf(sq, 0.f)) * (-0.5f * LOG2E);
            float pv = exp2f(arg);
            p[j] = pv;
            lsum += pv;
        }

        char* pw = (char*)&p_lds[wave][0] + l15 * 80 + lhi * 8;
        uint2 w0 = { pkbf(p[0], p[1]), pkbf(p[2], p[3]) };
        uint2 w1 = { pkbf(p[4], p[5]), pkbf(p[6], p[7]) };
        *(uint2*)(pw) = w0;
        *(uint2*)(pw + 32) = w1;

        const short8 pa = *(const short8*)((const char*)&p_lds[wave][0] + l15 * 80 + lhi * 16);
        const char* mb = (const char*)&m_lds[buf][0];
        #pragma unroll
        for (int c0 = 0; c0 < 7; ++c0) {
            const int c = c0 * 16 + l15;
            short8 bm = *(const short8*)(mb + c * 64 + (((lhi + c + (c >> 2)) & 3) * 16));
            Oacc[c0] = __builtin_amdgcn_mfma_f32_16x16x32_bf16(pa, bm, Oacc[c0], 0, 0, 0);
        }

        __syncthreads();
    }

    lsum += __shfl_xor(lsum, 16); lsum += __shfl_xor(lsum, 32);
    const size_t crow = (size_t)chunk * BROWS;
    #pragma unroll
    for (int c0 = 0; c0 < 7; ++c0)
        #pragma unroll
        for (int r2 = 0; r2 < 4; ++r2)
            pO[(crow + qbase + lhi * 4 + r2) * CP + c0 * 16 + l15] = Oacc[c0][r2];
    if (lane < 16) pL[crow + qbase + lane] = lsum;
}

__global__ __launch_bounds__(128) void combine(
    const float* __restrict__ pO, const float* __restrict__ pL,
    float* __restrict__ out)
{
    const int r = blockIdx.x, c = threadIdx.x;
    if (c >= NC) return;
    float acc = 0.f, l = 0.f;
    #pragma unroll
    for (int i = 0; i < NS; ++i) {
        acc += pO[((size_t)i * BROWS + r) * CP + c];
        l   += pL[(size_t)i * BROWS + r];
    }
    out[(size_t)r * NC + c] = acc / l;
}

// ================= fallback path (round-0, proven pass, 14.9 MB ws) =================
#define FBNS 16
#define FBCH 6250
#define KV 32
#define AST 136
#define MST 40
#define PST 40

__global__ __launch_bounds__(256, 2) void fused_fb(
    const float* __restrict__ x, const float* __restrict__ A,
    const float* __restrict__ M, float* __restrict__ pO,
    float* __restrict__ pM, float* __restrict__ pL)
{
    __shared__ __align__(16) unsigned short a_lds[KV * AST];
    __shared__ __align__(16) unsigned short mt_lds[CP * MST];
    __shared__ __align__(16) unsigned short p_lds[4][16 * PST];
    __shared__ float anorm_s[KV];

    const int tid  = threadIdx.x;
    const int wave = tid >> 6, lane = tid & 63;
    const int l15  = lane & 15, lhi = lane >> 4;
    const int bid  = blockIdx.x;
    const int chunk = bid & (FBNS - 1);
    const int rg    = bid >> 4;
    const int n0c   = chunk * FBCH;
    const int n1c   = n0c + FBCH;
    const int qbase = rg * 64 + wave * 16;
    const int q     = qbase + l15;

    short8 qf[4];
    float sumsq = 0.f;
    #pragma unroll
    for (int kk = 0; kk < 4; ++kk) {
        const float* xp = x + (size_t)q * BD + kk * 32 + lhi * 8;
        float4 v0 = *(const float4*)xp;
        float4 v1 = *(const float4*)(xp + 4);
        short8 f;
        f[0] = (short)f2bf(v0.x); f[1] = (short)f2bf(v0.y);
        f[2] = (short)f2bf(v0.z); f[3] = (short)f2bf(v0.w);
        f[4] = (short)f2bf(v1.x); f[5] = (short)f2bf(v1.y);
        f[6] = (short)f2bf(v1.z); f[7] = (short)f2bf(v1.w);
        qf[kk] = f;
        sumsq += v0.x*v0.x + v0.y*v0.y + v0.z*v0.z + v0.w*v0.w
               + v1.x*v1.x + v1.y*v1.y + v1.z*v1.z + v1.w*v1.w;
    }
    sumsq += __shfl_xor(sumsq, 16);
    sumsq += __shfl_xor(sumsq, 32);
    float nxr[4];
    #pragma unroll
    for (int r2 = 0; r2 < 4; ++r2) nxr[r2] = __shfl(sumsq, lhi * 4 + r2);

    const f32x4 zf = {0.f, 0.f, 0.f, 0.f};
    f32x4 Oacc[7];
    #pragma unroll
    for (int c = 0; c < 7; ++c) Oacc[c] = zf;
    float mrow[4] = {-1e30f, -1e30f, -1e30f, -1e30f};
    float lrow[4] = {0.f, 0.f, 0.f, 0.f};

    for (int n0 = n0c; n0 < n1c; n0 += KV) {
        __syncthreads();
        {
            int arow = tid >> 3, seg = tid & 7;
            int n = n0 + arow;
            float s2 = 0.f;
            unsigned short* dst = &a_lds[arow * AST + seg * 16];
            if (n < n1c) {
                const float* src = A + (size_t)n * BD + seg * 16;
                #pragma unroll
                for (int j = 0; j < 4; ++j) {
                    float4 v = ((const float4*)src)[j];
                    dst[j*4+0] = f2bf(v.x); dst[j*4+1] = f2bf(v.y);
                    dst[j*4+2] = f2bf(v.z); dst[j*4+3] = f2bf(v.w);
                    s2 += v.x*v.x + v.y*v.y + v.z*v.z + v.w*v.w;
                }
            } else {
                #pragma unroll
                for (int j = 0; j < 16; ++j) dst[j] = 0;
            }
            s2 += __shfl_xor(s2, 1);
            s2 += __shfl_xor(s2, 2);
            s2 += __shfl_xor(s2, 4);
            if (seg == 0) anorm_s[arow] = (n < n1c) ? s2 : 1e18f;
        }
        #pragma unroll
        for (int it = 0; it < 14; ++it) {
            int idx = tid + it * 256;
            int r2 = idx / CP;
            int c  = idx - r2 * CP;
            int n  = n0 + r2;
            float v = (c < NC && n < n1c) ? M[(size_t)n * NC + c] : 0.f;
            mt_lds[c * MST + r2] = f2bf(v);
        }
        __syncthreads();

        f32x4 s[2]; s[0] = zf; s[1] = zf;
        #pragma unroll
        for (int t = 0; t < 2; ++t) {
            #pragma unroll
            for (int kk = 0; kk < 4; ++kk) {
                short8 bf = *(const short8*)&a_lds[(t*16 + l15) * AST + kk*32 + lhi*8];
                s[t] = __builtin_amdgcn_mfma_f32_16x16x32_bf16(qf[kk], bf, s[t], 0, 0, 0);
            }
        }
        float na0 = anorm_s[l15], na1 = anorm_s[16 + l15];

        float pv0[4], pv1[4], fr[4];
        #pragma unroll
        for (int r2 = 0; r2 < 4; ++r2) {
            float s0 = nxr[r2] + na0 - 2.f * s[0][r2];
            float s1 = nxr[r2] + na1 - 2.f * s[1][r2];
            s0 = -0.5f * sqrtf(fmaxf(s0, 0.f));
            s1 = -0.5f * sqrtf(fmaxf(s1, 0.f));
            float v = fmaxf(s0, s1);
            v = fmaxf(v, __shfl_xor(v, 1));
            v = fmaxf(v, __shfl_xor(v, 2));
            v = fmaxf(v, __shfl_xor(v, 4));
            v = fmaxf(v, __shfl_xor(v, 8));
            float mnew = fmaxf(mrow[r2], v);
            float f = exp2f((mrow[r2] - mnew) * LOG2E);
            mrow[r2] = mnew;
            float p0 = exp2f((s0 - mnew) * LOG2E);
            float p1 = exp2f((s1 - mnew) * LOG2E);
            pv0[r2] = p0; pv1[r2] = p1;
            float ps = p0 + p1;
            ps += __shfl_xor(ps, 1);
            ps += __shfl_xor(ps, 2);
            ps += __shfl_xor(ps, 4);
            ps += __shfl_xor(ps, 8);
            lrow[r2] = lrow[r2] * f + ps;
            fr[r2] = f;
        }
        #pragma unroll
        for (int c = 0; c < 7; ++c)
            #pragma unroll
            for (int r2 = 0; r2 < 4; ++r2) Oacc[c][r2] *= fr[r2];

        #pragma unroll
        for (int r2 = 0; r2 < 4; ++r2) {
            p_lds[wave][(lhi*4 + r2) * PST +  0 + l15] = f2bf(pv0[r2]);
            p_lds[wave][(lhi*4 + r2) * PST + 16 + l15] = f2bf(pv1[r2]);
        }
        short8 pa = *(const short8*)&p_lds[wave][l15 * PST + lhi * 8];
        #pragma unroll
        for (int c = 0; c < 7; ++c) {
            short8 bm = *(const short8*)&mt_lds[(c*16 + l15) * MST + lhi * 8];
            Oacc[c] = __builtin_amdgcn_mfma_f32_16x16x32_bf16(pa, bm, Oacc[c], 0, 0, 0);
        }
    }

    const size_t crow = (size_t)chunk * 2048;
    #pragma unroll
    for (int c = 0; c < 7; ++c) {
        #pragma unroll
        for (int r2 = 0; r2 < 4; ++r2) {
            int row = qbase + lhi * 4 + r2;
            pO[(crow + row) * CP + c * 16 + l15] = Oacc[c][r2];
        }
    }
    if (l15 == 0) {
        #pragma unroll
        for (int r2 = 0; r2 < 4; ++r2) {
            int row = qbase + lhi * 4 + r2;
            pM[crow + row] = mrow[r2];
            pL[crow + row] = lrow[r2];
        }
    }
}

__global__ __launch_bounds__(128) void combine_fb(
    const float* __restrict__ pO, const float* __restrict__ pM,
    const float* __restrict__ pL, float* __restrict__ out)
{
    int r = blockIdx.x;
    int c = threadIdx.x;
    float mi[FBNS];
    float mg = -1e30f;
    #pragma unroll
    for (int i = 0; i < FBNS; ++i) { mi[i] = pM[i * 2048 + r]; mg = fmaxf(mg, mi[i]); }
    float w[FBNS];
    float lg = 0.f;
    #pragma unroll
    for (int i = 0; i < FBNS; ++i) {
        w[i] = exp2f((mi[i] - mg) * LOG2E);
        lg += pL[i * 2048 + r] * w[i];
    }
    if (c < NC) {
        float acc = 0.f;
        #pragma unroll
        for (int i = 0; i < FBNS; ++i)
            acc += pO[((size_t)i * 2048 + r) * CP + c] * w[i];
        out[(size_t)r * NC + c] = acc / lg;
    }
}

extern "C" void kernel_launch(void* const* d_in, const int* in_sizes, int n_in,
                              void* d_out, int out_size, void* d_ws, size_t ws_size,
                              hipStream_t stream) {
    const float* x = (const float*)d_in[0];
    const float* A = (const float*)d_in[1];
    const float* M = (const float*)d_in[2];
    float* out = (float*)d_out;

    const size_t FULL = 78022272;  // Abf + anorm + Mt + pO + pL
    if (ws_size >= FULL) {
        unsigned short* Abf = (unsigned short*)d_ws;
        float* anorm = (float*)(Abf + (size_t)NTOT * BD);
        unsigned short* Mt = (unsigned short*)(anorm + NTOT);
        float* pO = (float*)(Mt + (size_t)CP * NTOT);
        float* pL = pO + (size_t)NS * BROWS * CP;
        prep_A<<<6250, 256, 0, stream>>>(A, Abf, anorm);
        prep_M<<<dim3(391, 14), 256, 0, stream>>>(M, Mt);
        fused_main<<<1024, 256, 0, stream>>>(x, Abf, anorm, Mt, pO, pL);
        combine<<<2048, 128, 0, stream>>>(pO, pL, out);
    } else {
        float* pO = (float*)d_ws;
        float* pM = pO + (size_t)FBNS * 2048 * CP;
        float* pL = pM + (size_t)FBNS * 2048;
        fused_fb<<<512, 256, 0, stream>>>(x, A, M, pO, pM, pL);
        combine_fb<<<2048, 128, 0, stream>>>(pO, pM, pL, out);
    }
}

// Round 12
// 282.801 us; speedup vs baseline: 5.2029x; 1.7138x over previous
//
#include <hip/hip_runtime.h>

// ---------------- fast-path constants ----------------
#define NTOT 100000
#define BD 128
#define NC 100
#define CP 112
#define NS 32
#define BROWS 2048
#define LOG2E 1.4426950408889634f

typedef short short8 __attribute__((ext_vector_type(8)));
typedef float f32x4 __attribute__((ext_vector_type(4)));

__device__ __forceinline__ unsigned short f2bf(float f) {
    union { float f; unsigned u; } v; v.f = f;
    unsigned r = v.u + 0x7FFFu + ((v.u >> 16) & 1u);
    return (unsigned short)(r >> 16);
}

__device__ __forceinline__ unsigned pkbf(float a, float b) {
    unsigned r;
    asm("v_cvt_pk_bf16_f32 %0, %1, %2" : "=v"(r) : "v"(a), "v"(b));
    return r;
}

__device__ __forceinline__ float rawsqrt(float x) {
    float r;
    asm("v_sqrt_f32 %0, %1" : "=v"(r) : "v"(x));
    return r;
}

__device__ __forceinline__ float rawexp2(float x) {
    float r;
    asm("v_exp_f32 %0, %1" : "=v"(r) : "v"(x));
    return r;
}

__device__ __forceinline__ void gload16(const void* g, void* l) {
    __builtin_amdgcn_global_load_lds((const __attribute__((address_space(1))) void*)g,
                                     (__attribute__((address_space(3))) void*)l, 16, 0, 0);
}

// ---- prep: A (f32) -> Abf (bf16, per-row XOR-swizzled) + anorm = ||A_n||^2
__global__ __launch_bounds__(256) void prep_A(const float* __restrict__ A,
                                              unsigned short* __restrict__ Abf,
                                              float* __restrict__ anorm) {
    const int tid = threadIdx.x;
    const int row = blockIdx.x * 16 + (tid >> 4);
    const int g = tid & 15;
    const float* src = A + (size_t)row * BD + g * 8;
    float4 v0 = *(const float4*)src, v1 = *(const float4*)(src + 4);
    uint4 u;
    u.x = pkbf(v0.x, v0.y); u.y = pkbf(v0.z, v0.w);
    u.z = pkbf(v1.x, v1.y); u.w = pkbf(v1.z, v1.w);
    float ss = v0.x*v0.x + v0.y*v0.y + v0.z*v0.z + v0.w*v0.w
             + v1.x*v1.x + v1.y*v1.y + v1.z*v1.z + v1.w*v1.w;
    ss += __shfl_xor(ss, 1); ss += __shfl_xor(ss, 2);
    ss += __shfl_xor(ss, 4); ss += __shfl_xor(ss, 8);
    *(uint4*)((char*)Abf + (size_t)row * 256 + ((g * 16) ^ ((row & 15) << 4))) = u;
    if (g == 0) anorm[row] = ss;
}

// ---- prep: M (f32 [N][100]) -> Mt (bf16 [112][N]) via coalesced LDS transpose
__global__ __launch_bounds__(256) void prep_M(const float* __restrict__ M,
                                              unsigned short* __restrict__ Mt) {
    __shared__ unsigned short lm[100 * 264];
    const int t = threadIdx.x;
    const int n0 = blockIdx.x * 256;
    const int rows = min(256, NTOT - n0);
    // phase 1: coalesced float4 reads; f = global f4 offset within block
    const float4* Mf4 = (const float4*)(M + (size_t)n0 * NC);
    #pragma unroll
    for (int k = 0; k < 25; ++k) {
        int f = k * 256 + t;
        if (f < rows * 25) {
            int row = (int)(((unsigned)f * 5243u) >> 17);   // f / 25
            int c4 = f - row * 25;
            float4 v = Mf4[f];
            lm[(c4 * 4 + 0) * 264 + row] = f2bf(v.x);
            lm[(c4 * 4 + 1) * 264 + row] = f2bf(v.y);
            lm[(c4 * 4 + 2) * 264 + row] = f2bf(v.z);
            lm[(c4 * 4 + 3) * 264 + row] = f2bf(v.w);
        }
    }
    __syncthreads();
    // phase 2: coalesced writes, 512B per c-row
    if (n0 + t < NTOT) {
        for (int c = 0; c < NC; ++c)
            Mt[(size_t)c * NTOT + n0 + t] = lm[c * 264 + t];
        #pragma unroll
        for (int z = NC; z < CP; ++z)
            Mt[(size_t)z * NTOT + n0 + t] = 0;
    }
}

// ---- fused flash-softmin: each wave owns 32 q rows (2 x 16 sub-tiles)
__global__ __launch_bounds__(256, 2) void fused_main(
    const float* __restrict__ x, const unsigned short* __restrict__ Abf,
    const float* __restrict__ anorm, const unsigned short* __restrict__ Mt,
    float* __restrict__ pO, float* __restrict__ pL)
{
    __shared__ __align__(16) unsigned short a_lds[2][4096];  // 2 x 32 rows x 256B
    __shared__ __align__(16) unsigned short m_lds[2][3584];  // 2 x 112 rows x 64B
    __shared__ __align__(16) unsigned short p_lds[8][640];   // [wave*2+t][16 x 40]

    const int tid = threadIdx.x, wave = tid >> 6, lane = tid & 63;
    const int l15 = lane & 15, lhi = lane >> 4;
    const int bid = blockIdx.x;
    const int chunk = bid & (NS - 1), rg = bid >> 5;
    const int ts = chunk * 97 + (chunk < 21 ? chunk : 21);
    const int tiles = (chunk < 21) ? 98 : 97;
    const int n0c = ts * 32;
    const int qbw = rg * 128 + wave * 32;   // wave's 32-q base

    // ---- Q fragments (2 sub-tiles x 4 kk) + ||x||^2 per sub-tile
    short8 qf[2][4];
    float nx[2];
    #pragma unroll
    for (int t = 0; t < 2; ++t) {
        float s = 0.f;
        #pragma unroll
        for (int kk = 0; kk < 4; ++kk) {
            const float* xp = x + (size_t)(qbw + t * 16 + l15) * BD + kk * 32 + lhi * 8;
            float4 v0 = *(const float4*)xp, v1 = *(const float4*)(xp + 4);
            uint4 uu;
            uu.x = pkbf(v0.x, v0.y); uu.y = pkbf(v0.z, v0.w);
            uu.z = pkbf(v1.x, v1.y); uu.w = pkbf(v1.z, v1.w);
            qf[t][kk] = *(short8*)&uu;
            s += v0.x*v0.x + v0.y*v0.y + v0.z*v0.z + v0.w*v0.w
               + v1.x*v1.x + v1.y*v1.y + v1.z*v1.z + v1.w*v1.w;
        }
        s += __shfl_xor(s, 16); s += __shfl_xor(s, 32);
        nx[t] = s;
    }

    // hoisted staging addresses (identical to verified v1)
    const char* aFix = (const char*)Abf + tid * 16;
    const int r0 = tid >> 2, sg0 = ((tid & 3) - r0 - (r0 >> 2)) & 3;
    const char* mFix0 = (const char*)Mt + (size_t)r0 * (NTOT * 2) + sg0 * 16;
    const int L1 = tid + 256, r1 = L1 >> 2, sg1 = ((L1 & 3) - r1 - (r1 >> 2)) & 3;
    const char* mFix1 = (const char*)Mt + (size_t)r1 * (NTOT * 2) + sg1 * 16;

    auto stage = [&](int buf, int t) {
        const int n0 = n0c + t * 32;
        const char* ab = aFix + (size_t)n0 * 256;
        char* al = (char*)&a_lds[buf][0] + tid * 16;
        gload16(ab, al);
        gload16(ab + 4096, al + 4096);
        gload16(mFix0 + (size_t)n0 * 2, (char*)&m_lds[buf][0] + tid * 16);
        if (tid < 192)
            gload16(mFix1 + (size_t)n0 * 2, (char*)&m_lds[buf][0] + (tid + 256) * 16);
    };

    f32x4 Oacc[2][7];
    const f32x4 zf = {0.f, 0.f, 0.f, 0.f};
    #pragma unroll
    for (int t = 0; t < 2; ++t)
        #pragma unroll
        for (int c0 = 0; c0 < 7; ++c0) Oacc[t][c0] = zf;
    float lsum[2] = {0.f, 0.f};

    stage(0, 0);
    __syncthreads();

    for (int it = 0; it < tiles; ++it) {
        const int buf = it & 1;
        const int n0 = n0c + it * 32;
        if (it + 1 < tiles) stage(buf ^ 1, it + 1);

        float an[8];
        #pragma unroll
        for (int j = 0; j < 8; ++j)
            an[j] = anorm[n0 + (j >> 2) * 16 + lhi * 4 + (j & 3)];

        // ---- QK^T for both sub-tiles off one A-tile read
        f32x4 s0[2], s1[2];
        s0[0] = zf; s0[1] = zf; s1[0] = zf; s1[1] = zf;
        const char* ab = (const char*)&a_lds[buf][0];
        #pragma unroll
        for (int kk = 0; kk < 4; ++kk) {
            const int sw = (kk * 64 + lhi * 16) ^ (l15 << 4);
            short8 b0 = *(const short8*)(ab + l15 * 256 + sw);
            short8 b1 = *(const short8*)(ab + (16 + l15) * 256 + sw);
            s0[0] = __builtin_amdgcn_mfma_f32_16x16x32_bf16(b0, qf[0][kk], s0[0], 0, 0, 0);
            s1[0] = __builtin_amdgcn_mfma_f32_16x16x32_bf16(b1, qf[0][kk], s1[0], 0, 0, 0);
            s0[1] = __builtin_amdgcn_mfma_f32_16x16x32_bf16(b0, qf[1][kk], s0[1], 0, 0, 0);
            s1[1] = __builtin_amdgcn_mfma_f32_16x16x32_bf16(b1, qf[1][kk], s1[1], 0, 0, 0);
        }

        // ---- softmin weights, no max tracking (scores <= 0)
        #pragma unroll
        for (int t = 0; t < 2; ++t) {
            float p[8];
            #pragma unroll
            for (int j = 0; j < 8; ++j) {
                float sv = (j < 4) ? s0[t][j & 3] : s1[t][j & 3];
                float sq = fmaf(sv, -2.f, an[j]) + nx[t];
                float d = rawsqrt(fmaxf(sq, 0.f));
                float pv = rawexp2(d * (-0.5f * LOG2E));
                p[j] = pv;
                lsum[t] += pv;
            }
            char* pw = (char*)&p_lds[wave * 2 + t][0] + l15 * 80 + lhi * 8;
            uint2 w0 = { pkbf(p[0], p[1]), pkbf(p[2], p[3]) };
            uint2 w1 = { pkbf(p[4], p[5]), pkbf(p[6], p[7]) };
            *(uint2*)(pw) = w0;
            *(uint2*)(pw + 32) = w1;
        }

        // ---- PV: one M-frag read feeds both sub-tiles
        const short8 pa0 = *(const short8*)((const char*)&p_lds[wave * 2 + 0][0] + l15 * 80 + lhi * 16);
        const short8 pa1 = *(const short8*)((const char*)&p_lds[wave * 2 + 1][0] + l15 * 80 + lhi * 16);
        const char* mb = (const char*)&m_lds[buf][0];
        #pragma unroll
        for (int c0 = 0; c0 < 7; ++c0) {
            const int c = c0 * 16 + l15;
            short8 bm = *(const short8*)(mb + c * 64 + (((lhi + c + (c >> 2)) & 3) * 16));
            Oacc[0][c0] = __builtin_amdgcn_mfma_f32_16x16x32_bf16(pa0, bm, Oacc[0][c0], 0, 0, 0);
            Oacc[1][c0] = __builtin_amdgcn_mfma_f32_16x16x32_bf16(pa1, bm, Oacc[1][c0], 0, 0, 0);
        }

        __syncthreads();
    }

    // ---- write partials
    const size_t crow = (size_t)chunk * BROWS;
    #pragma unroll
    for (int t = 0; t < 2; ++t) {
        float ls = lsum[t];
        ls += __shfl_xor(ls, 16); ls += __shfl_xor(ls, 32);
        #pragma unroll
        for (int c0 = 0; c0 < 7; ++c0)
            #pragma unroll
            for (int r2 = 0; r2 < 4; ++r2)
                pO[(crow + qbw + t * 16 + lhi * 4 + r2) * CP + c0 * 16 + l15] = Oacc[t][c0][r2];
        if (lane < 16) pL[crow + qbw + t * 16 + lane] = ls;
    }
}

__global__ __launch_bounds__(128) void combine(
    const float* __restrict__ pO, const float* __restrict__ pL,
    float* __restrict__ out)
{
    const int r = blockIdx.x, c = threadIdx.x;
    if (c >= NC) return;
    float acc = 0.f, l = 0.f;
    #pragma unroll
    for (int i = 0; i < NS; ++i) {
        acc += pO[((size_t)i * BROWS + r) * CP + c];
        l   += pL[(size_t)i * BROWS + r];
    }
    out[(size_t)r * NC + c] = acc / l;
}

// ================= fallback path (round-0, proven pass, 14.9 MB ws) =================
#define FBNS 16
#define FBCH 6250
#define KV 32
#define AST 136
#define MST 40
#define PST 40

__global__ __launch_bounds__(256, 2) void fused_fb(
    const float* __restrict__ x, const float* __restrict__ A,
    const float* __restrict__ M, float* __restrict__ pO,
    float* __restrict__ pM, float* __restrict__ pL)
{
    __shared__ __align__(16) unsigned short a_lds[KV * AST];
    __shared__ __align__(16) unsigned short mt_lds[CP * MST];
    __shared__ __align__(16) unsigned short p_lds[4][16 * PST];
    __shared__ float anorm_s[KV];

    const int tid  = threadIdx.x;
    const int wave = tid >> 6, lane = tid & 63;
    const int l15  = lane & 15, lhi = lane >> 4;
    const int bid  = blockIdx.x;
    const int chunk = bid & (FBNS - 1);
    const int rg    = bid >> 4;
    const int n0c   = chunk * FBCH;
    const int n1c   = n0c + FBCH;
    const int qbase = rg * 64 + wave * 16;
    const int q     = qbase + l15;

    short8 qf[4];
    float sumsq = 0.f;
    #pragma unroll
    for (int kk = 0; kk < 4; ++kk) {
        const float* xp = x + (size_t)q * BD + kk * 32 + lhi * 8;
        float4 v0 = *(const float4*)xp;
        float4 v1 = *(const float4*)(xp + 4);
        short8 f;
        f[0] = (short)f2bf(v0.x); f[1] = (short)f2bf(v0.y);
        f[2] = (short)f2bf(v0.z); f[3] = (short)f2bf(v0.w);
        f[4] = (short)f2bf(v1.x); f[5] = (short)f2bf(v1.y);
        f[6] = (short)f2bf(v1.z); f[7] = (short)f2bf(v1.w);
        qf[kk] = f;
        sumsq += v0.x*v0.x + v0.y*v0.y + v0.z*v0.z + v0.w*v0.w
               + v1.x*v1.x + v1.y*v1.y + v1.z*v1.z + v1.w*v1.w;
    }
    sumsq += __shfl_xor(sumsq, 16);
    sumsq += __shfl_xor(sumsq, 32);
    float nxr[4];
    #pragma unroll
    for (int r2 = 0; r2 < 4; ++r2) nxr[r2] = __shfl(sumsq, lhi * 4 + r2);

    const f32x4 zf = {0.f, 0.f, 0.f, 0.f};
    f32x4 Oacc[7];
    #pragma unroll
    for (int c = 0; c < 7; ++c) Oacc[c] = zf;
    float mrow[4] = {-1e30f, -1e30f, -1e30f, -1e30f};
    float lrow[4] = {0.f, 0.f, 0.f, 0.f};

    for (int n0 = n0c; n0 < n1c; n0 += KV) {
        __syncthreads();
        {
            int arow = tid >> 3, seg = tid & 7;
            int n = n0 + arow;
            float s2 = 0.f;
            unsigned short* dst = &a_lds[arow * AST + seg * 16];
            if (n < n1c) {
                const float* src = A + (size_t)n * BD + seg * 16;
                #pragma unroll
                for (int j = 0; j < 4; ++j) {
                    float4 v = ((const float4*)src)[j];
                    dst[j*4+0] = f2bf(v.x); dst[j*4+1] = f2bf(v.y);
                    dst[j*4+2] = f2bf(v.z); dst[j*4+3] = f2bf(v.w);
                    s2 += v.x*v.x + v.y*v.y + v.z*v.z + v.w*v.w;
                }
            } else {
                #pragma unroll
                for (int j = 0; j < 16; ++j) dst[j] = 0;
            }
            s2 += __shfl_xor(s2, 1);
            s2 += __shfl_xor(s2, 2);
            s2 += __shfl_xor(s2, 4);
            if (seg == 0) anorm_s[arow] = (n < n1c) ? s2 : 1e18f;
        }
        #pragma unroll
        for (int it = 0; it < 14; ++it) {
            int idx = tid + it * 256;
            int r2 = idx / CP;
            int c  = idx - r2 * CP;
            int n  = n0 + r2;
            float v = (c < NC && n < n1c) ? M[(size_t)n * NC + c] : 0.f;
            mt_lds[c * MST + r2] = f2bf(v);
        }
        __syncthreads();

        f32x4 s[2]; s[0] = zf; s[1] = zf;
        #pragma unroll
        for (int t = 0; t < 2; ++t) {
            #pragma unroll
            for (int kk = 0; kk < 4; ++kk) {
                short8 bf = *(const short8*)&a_lds[(t*16 + l15) * AST + kk*32 + lhi*8];
                s[t] = __builtin_amdgcn_mfma_f32_16x16x32_bf16(qf[kk], bf, s[t], 0, 0, 0);
            }
        }
        float na0 = anorm_s[l15], na1 = anorm_s[16 + l15];

        float pv0[4], pv1[4], fr[4];
        #pragma unroll
        for (int r2 = 0; r2 < 4; ++r2) {
            float s0 = nxr[r2] + na0 - 2.f * s[0][r2];
            float s1 = nxr[r2] + na1 - 2.f * s[1][r2];
            s0 = -0.5f * sqrtf(fmaxf(s0, 0.f));
            s1 = -0.5f * sqrtf(fmaxf(s1, 0.f));
            float v = fmaxf(s0, s1);
            v = fmaxf(v, __shfl_xor(v, 1));
            v = fmaxf(v, __shfl_xor(v, 2));
            v = fmaxf(v, __shfl_xor(v, 4));
            v = fmaxf(v, __shfl_xor(v, 8));
            float mnew = fmaxf(mrow[r2], v);
            float f = exp2f((mrow[r2] - mnew) * LOG2E);
            mrow[r2] = mnew;
            float p0 = exp2f((s0 - mnew) * LOG2E);
            float p1 = exp2f((s1 - mnew) * LOG2E);
            pv0[r2] = p0; pv1[r2] = p1;
            float ps = p0 + p1;
            ps += __shfl_xor(ps, 1);
            ps += __shfl_xor(ps, 2);
            ps += __shfl_xor(ps, 4);
            ps += __shfl_xor(ps, 8);
            lrow[r2] = lrow[r2] * f + ps;
            fr[r2] = f;
        }
        #pragma unroll
        for (int c = 0; c < 7; ++c)
            #pragma unroll
            for (int r2 = 0; r2 < 4; ++r2) Oacc[c][r2] *= fr[r2];

        #pragma unroll
        for (int r2 = 0; r2 < 4; ++r2) {
            p_lds[wave][(lhi*4 + r2) * PST +  0 + l15] = f2bf(pv0[r2]);
            p_lds[wave][(lhi*4 + r2) * PST + 16 + l15] = f2bf(pv1[r2]);
        }
        short8 pa = *(const short8*)&p_lds[wave][l15 * PST + lhi * 8];
        #pragma unroll
        for (int c = 0; c < 7; ++c) {
            short8 bm = *(const short8*)&mt_lds[(c*16 + l15) * MST + lhi * 8];
            Oacc[c] = __builtin_amdgcn_mfma_f32_16x16x32_bf16(pa, bm, Oacc[c], 0, 0, 0);
        }
    }

    const size_t crow = (size_t)chunk * 2048;
    #pragma unroll
    for (int c = 0; c < 7; ++c) {
        #pragma unroll
        for (int r2 = 0; r2 < 4; ++r2) {
            int row = qbase + lhi * 4 + r2;
            pO[(crow + row) * CP + c * 16 + l15] = Oacc[c][r2];
        }
    }
    if (l15 == 0) {
        #pragma unroll
        for (int r2 = 0; r2 < 4; ++r2) {
            int row = qbase + lhi * 4 + r2;
            pM[crow + row] = mrow[r2];
            pL[crow + row] = lrow[r2];
        }
    }
}

__global__ __launch_bounds__(128) void combine_fb(
    const float* __restrict__ pO, const float* __restrict__ pM,
    const float* __restrict__ pL, float* __restrict__ out)
{
    int r = blockIdx.x;
    int c = threadIdx.x;
    float mi[FBNS];
    float mg = -1e30f;
    #pragma unroll
    for (int i = 0; i < FBNS; ++i) { mi[i] = pM[i * 2048 + r]; mg = fmaxf(mg, mi[i]); }
    float w[FBNS];
    float lg = 0.f;
    #pragma unroll
    for (int i = 0; i < FBNS; ++i) {
        w[i] = exp2f((mi[i] - mg) * LOG2E);
        lg += pL[i * 2048 + r] * w[i];
    }
    if (c < NC) {
        float acc = 0.f;
        #pragma unroll
        for (int i = 0; i < FBNS; ++i)
            acc += pO[((size_t)i * 2048 + r) * CP + c] * w[i];
        out[(size_t)r * NC + c] = acc / lg;
    }
}

extern "C" void kernel_launch(void* const* d_in, const int* in_sizes, int n_in,
                              void* d_out, int out_size, void* d_ws, size_t ws_size,
                              hipStream_t stream) {
    const float* x = (const float*)d_in[0];
    const float* A = (const float*)d_in[1];
    const float* M = (const float*)d_in[2];
    float* out = (float*)d_out;

    const size_t FULL = 78022272;  // Abf + anorm + Mt + pO + pL
    if (ws_size >= FULL) {
        unsigned short* Abf = (unsigned short*)d_ws;
        float* anorm = (float*)(Abf + (size_t)NTOT * BD);
        unsigned short* Mt = (unsigned short*)(anorm + NTOT);
        float* pO = (float*)(Mt + (size_t)CP * NTOT);
        float* pL = pO + (size_t)NS * BROWS * CP;
        prep_A<<<6250, 256, 0, stream>>>(A, Abf, anorm);
        prep_M<<<391, 256, 0, stream>>>(M, Mt);
        fused_main<<<512, 256, 0, stream>>>(x, Abf, anorm, Mt, pO, pL);
        combine<<<2048, 128, 0, stream>>>(pO, pL, out);
    } else {
        float* pO = (float*)d_ws;
        float* pM = pO + (size_t)FBNS * 2048 * CP;
        float* pL = pM + (size_t)FBNS * 2048;
        fused_fb<<<512, 256, 0, stream>>>(x, A, M, pO, pM, pL);
        combine_fb<<<2048, 128, 0, stream>>>(pO, pM, pL, out);
    }
}